// Round 7
// baseline (380.959 us; speedup 1.0000x reference)
//
#include <hip/hip_runtime.h>
#include <math.h>

#define NG 256     // NUM_GRAPHS
#define NBLK 256   // blocks in histogram / pair-scatter passes
// bucket = target >> 9 (512 nodes per bucket, NB<=256); src packs in 17 bits (N <= 131072)

typedef unsigned short ushort_t;

__device__ __forceinline__ float lo16(unsigned u) { return __uint_as_float(u << 16); }
__device__ __forceinline__ float hi16(unsigned u) { return __uint_as_float(u & 0xffff0000u); }
__device__ __forceinline__ ushort_t f2bf(float x) {   // round-to-nearest-even
    unsigned u = __float_as_uint(x);
    unsigned r = (u + 0x7FFFu + ((u >> 16) & 1u)) >> 16;
    return (ushort_t)r;
}

// ---------------------------------------------------------------------------
// K1: per-block histogram of edge targets into NB buckets (LDS atomics only);
// raw counts go to blockOff[bucket][block]. No global atomics, no memset needed.
__global__ __launch_bounds__(256) void hist_bucket_kernel(
        const int* __restrict__ col, int* __restrict__ blockOff, int E, int NB) {
    __shared__ int h[256];
    h[threadIdx.x] = 0;
    __syncthreads();
    const int chunk = (E + NBLK - 1) / NBLK;
    const int beg = blockIdx.x * chunk;
    const int end = min(beg + chunk, E);
    for (int e = beg + threadIdx.x; e < end; e += 256)
        atomicAdd(&h[col[e] >> 9], 1);
    __syncthreads();
    if (threadIdx.x < NB) blockOff[threadIdx.x * NBLK + blockIdx.x] = h[threadIdx.x];
}

// K2 (one block, 1024 thr): converts raw counts into absolute scatter offsets.
//  step1: per-bucket exclusive scan over the 256 block counts (one wave/bucket)
//  step2: exclusive scan over bucket totals -> bucketBase
//  step3: add bucketBase into blockOff, write bucketBase to global
__global__ __launch_bounds__(1024) void offsets_kernel(
        int* __restrict__ blockOff, int* __restrict__ bucketBase, int NB) {
    __shared__ int bsum[256];
    __shared__ int bbase[256];
    const int t = threadIdx.x;
    const int w = t >> 6, ln = t & 63;
    if (t < 256) bsum[t] = 0;
    __syncthreads();
    for (int b = w; b < NB; b += 16) {
        int idx = b * NBLK + ln * 4;
        int c0 = blockOff[idx + 0], c1 = blockOff[idx + 1];
        int c2 = blockOff[idx + 2], c3 = blockOff[idx + 3];
        int s = c0 + c1 + c2 + c3;
        int inc = s;
#pragma unroll
        for (int d = 1; d < 64; d <<= 1) {
            int u = __shfl_up(inc, d, 64);
            if (ln >= d) inc += u;
        }
        int ex = inc - s;
        blockOff[idx + 0] = ex;
        blockOff[idx + 1] = ex + c0;
        blockOff[idx + 2] = ex + c0 + c1;
        blockOff[idx + 3] = ex + c0 + c1 + c2;
        if (ln == 63) bsum[b] = inc;
    }
    __syncthreads();
    if (w == 0) {
        int i0 = 4 * ln;
        int v0 = bsum[i0], v1 = bsum[i0 + 1], v2 = bsum[i0 + 2], v3 = bsum[i0 + 3];
        int s = v0 + v1 + v2 + v3;
        int inc = s;
#pragma unroll
        for (int d = 1; d < 64; d <<= 1) {
            int u = __shfl_up(inc, d, 64);
            if (ln >= d) inc += u;
        }
        int ex = inc - s;
        bbase[i0] = ex; bbase[i0 + 1] = ex + v0;
        bbase[i0 + 2] = ex + v0 + v1; bbase[i0 + 3] = ex + v0 + v1 + v2;
        int tot = __shfl(inc, 63, 64);
        if (ln == 0) bucketBase[NB] = tot;
    }
    __syncthreads();
    for (int b = w; b < NB; b += 16) {
        int base = bbase[b];
        int idx = b * NBLK + ln * 4;
        blockOff[idx + 0] += base;
        blockOff[idx + 1] += base;
        blockOff[idx + 2] += base;
        blockOff[idx + 3] += base;
        if (ln == 0) bucketBase[b] = base;
    }
}

// K3: scatter packed (local_tgt<<17 | src) pairs, grouped by bucket (LDS cursors;
// each (block,bucket) range is exclusive -> dense single-writer streams)
__global__ __launch_bounds__(256) void scatter_pairs_kernel(
        const int* __restrict__ ei, const int* __restrict__ blockOff,
        int* __restrict__ pairs, int E, int NB) {
    __shared__ int cur[256];
    if (threadIdx.x < NB) cur[threadIdx.x] = blockOff[threadIdx.x * NBLK + blockIdx.x];
    __syncthreads();
    const int chunk = (E + NBLK - 1) / NBLK;
    const int beg = blockIdx.x * chunk;
    const int end = min(beg + chunk, E);
    for (int e = beg + threadIdx.x; e < end; e += 256) {
        int src = ei[e];
        int tgt = ei[E + e];
        int pos = atomicAdd(&cur[tgt >> 9], 1);
        pairs[pos] = (int)(((unsigned)(tgt & 511) << 17) | (unsigned)src);
    }
}

// K4: one block per bucket (512 nodes): LDS 512-bin hist + scan -> rowptr, dinv, adj
__global__ __launch_bounds__(256) void csr_bucket_kernel(
        const int* __restrict__ pairs, const int* __restrict__ bucketBase,
        int* __restrict__ rowptr, int* __restrict__ adj,
        float* __restrict__ dinv, int N, int E) {
    __shared__ int h[512];
    __shared__ int sc[256];
    const int b = blockIdx.x, t = threadIdx.x;
    const int base = bucketBase[b];
    const int end = bucketBase[b + 1];
    h[t] = 0; h[t + 256] = 0;
    __syncthreads();
    for (int i = base + t; i < end; i += 256)
        atomicAdd(&h[((unsigned)pairs[i] >> 17) & 511], 1);
    __syncthreads();
    const int v0 = h[2 * t], v1 = h[2 * t + 1];
    const int s = v0 + v1;
    sc[t] = s;
    __syncthreads();
    for (int o = 1; o < 256; o <<= 1) {
        int u = (t >= o) ? sc[t - o] : 0;
        __syncthreads();
        sc[t] += u;
        __syncthreads();
    }
    const int ex = sc[t] - s;    // exclusive over thread chunks within bucket
    const int node = (b << 9) + 2 * t;
    if (node < N)     { rowptr[node]     = base + ex;      dinv[node]     = rsqrtf((float)v0 + 1.f); }
    if (node + 1 < N) { rowptr[node + 1] = base + ex + v0; dinv[node + 1] = rsqrtf((float)v1 + 1.f); }
    h[2 * t]     = base + ex;        // own bins only: no cross-thread hazard
    h[2 * t + 1] = base + ex + v0;
    __syncthreads();
    for (int i = base + t; i < end; i += 256) {
        unsigned p = (unsigned)pairs[i];
        int pos = atomicAdd(&h[(p >> 17) & 511], 1);
        adj[pos] = (int)(p & 0x1FFFFu);
    }
    if (b == 0 && t == 0) rowptr[N] = E;
}

// ---------------------------------------------------------------------------
// hs1[i][f] = bf16( (sum_k x[i][k] * W1[k][f]) * dinv[i] )   (32 -> 32)
__global__ __launch_bounds__(256) void hs1_kernel(
        const float* __restrict__ x, const float* __restrict__ W,
        const float* __restrict__ dinv, ushort_t* __restrict__ hs, int N) {
    __shared__ float Ws[32 * 32];
    for (int t = threadIdx.x; t < 1024; t += blockDim.x) Ws[t] = W[t];
    __syncthreads();
    int gid = blockIdx.x * blockDim.x + threadIdx.x;
    if (gid >= N * 32) return;
    int i = gid >> 5, f = gid & 31;
    const float* xr = x + (size_t)i * 32;
    float acc = 0.f;
#pragma unroll
    for (int k = 0; k < 32; k++) acc += xr[k] * Ws[k * 32 + f];
    hs[gid] = f2bf(acc * dinv[i]);
}

// gather layer 1 (32 bf16 feats/row, packed uint2 loads: 8 lanes/row, up to 4
// independent row loads in flight per lane) + fused finalize + hs2 staging:
//   h1 = relu(dinv*(gather(hs1) + hs1_self) + b1)     (LDS only, fp32)
//   hs2[i][fo] = bf16( dinv[i] * sum_k h1[i][k] * W2[k][fo] )  fo<24, pad 0
__global__ __launch_bounds__(256) void gather1_kernel(
        const int* __restrict__ rowptr, const int* __restrict__ adj,
        const uint2* __restrict__ hs1q, const float* __restrict__ dinv,
        const float* __restrict__ b1, const float* __restrict__ W2,
        ushort_t* __restrict__ hs2out, int N) {
    __shared__ float W2s[32 * 24];
    __shared__ float b1s[32];
    __shared__ float h1row[8][32];
    const int tid = threadIdx.x;
    for (int t = tid; t < 768; t += 256) W2s[t] = W2[t];
    if (tid < 32) b1s[tid] = b1[tid];

    const int node = blockIdx.x * 8 + (tid >> 5);
    const int n = tid >> 5;
    const int l = tid & 31;
    const int f4 = l & 7;        // feature quad: features 4*f4 .. 4*f4+3
    const int e4 = l >> 3;       // edge slot 0..3
    const bool valid = node < N;

    int beg = 0, cnt = 0;
    if (valid) { beg = rowptr[node]; cnt = rowptr[node + 1] - beg; }
    const int* ap = adj + beg;
    float a0 = 0.f, a1 = 0.f, a2 = 0.f, a3 = 0.f;
    int j = 0;
    for (; j + 16 <= cnt; j += 16) {          // 16 edges/iter: 4 row loads in flight
        int s0 = ap[j + e4];
        int s1 = ap[j + 4 + e4];
        int s2 = ap[j + 8 + e4];
        int s3 = ap[j + 12 + e4];
        uint2 v0 = hs1q[(size_t)s0 * 8 + f4];
        uint2 v1 = hs1q[(size_t)s1 * 8 + f4];
        uint2 v2 = hs1q[(size_t)s2 * 8 + f4];
        uint2 v3 = hs1q[(size_t)s3 * 8 + f4];
        a0 += lo16(v0.x); a1 += hi16(v0.x); a2 += lo16(v0.y); a3 += hi16(v0.y);
        a0 += lo16(v1.x); a1 += hi16(v1.x); a2 += lo16(v1.y); a3 += hi16(v1.y);
        a0 += lo16(v2.x); a1 += hi16(v2.x); a2 += lo16(v2.y); a3 += hi16(v2.y);
        a0 += lo16(v3.x); a1 += hi16(v3.x); a2 += lo16(v3.y); a3 += hi16(v3.y);
    }
    for (; j + 8 <= cnt; j += 8) {
        int s0 = ap[j + e4];
        int s1 = ap[j + 4 + e4];
        uint2 v0 = hs1q[(size_t)s0 * 8 + f4];
        uint2 v1 = hs1q[(size_t)s1 * 8 + f4];
        a0 += lo16(v0.x); a1 += hi16(v0.x); a2 += lo16(v0.y); a3 += hi16(v0.y);
        a0 += lo16(v1.x); a1 += hi16(v1.x); a2 += lo16(v1.y); a3 += hi16(v1.y);
    }
    for (; j + 4 <= cnt; j += 4) {
        int s0 = ap[j + e4];
        uint2 v0 = hs1q[(size_t)s0 * 8 + f4];
        a0 += lo16(v0.x); a1 += hi16(v0.x); a2 += lo16(v0.y); a3 += hi16(v0.y);
    }
    if (e4 < cnt - j) {                        // tail 0..3 edges
        int s0 = ap[j + e4];
        uint2 v0 = hs1q[(size_t)s0 * 8 + f4];
        a0 += lo16(v0.x); a1 += hi16(v0.x); a2 += lo16(v0.y); a3 += hi16(v0.y);
    }
    // fold the 4 edge slots (lane bits 3,4)
    a0 += __shfl_xor(a0, 8);  a0 += __shfl_xor(a0, 16);
    a1 += __shfl_xor(a1, 8);  a1 += __shfl_xor(a1, 16);
    a2 += __shfl_xor(a2, 8);  a2 += __shfl_xor(a2, 16);
    a3 += __shfl_xor(a3, 8);  a3 += __shfl_xor(a3, 16);

    __syncthreads();   // weight/bias staging visibility (all threads reach here)

    float di = 0.f;
    if (valid) {
        di = dinv[node];
        uint2 sv = hs1q[(size_t)node * 8 + f4];   // self-loop term
        if (e4 == 0) {
            h1row[n][4 * f4 + 0] = fmaxf(di * (a0 + lo16(sv.x)) + b1s[4 * f4 + 0], 0.f);
            h1row[n][4 * f4 + 1] = fmaxf(di * (a1 + hi16(sv.x)) + b1s[4 * f4 + 1], 0.f);
            h1row[n][4 * f4 + 2] = fmaxf(di * (a2 + lo16(sv.y)) + b1s[4 * f4 + 2], 0.f);
            h1row[n][4 * f4 + 3] = fmaxf(di * (a3 + hi16(sv.y)) + b1s[4 * f4 + 3], 0.f);
        }
    }
    // same-wave producer/consumer through LDS: no barrier needed
    if (valid) {
        const int f = l;
        float a = 0.f;
        if (f < 24) {
#pragma unroll
            for (int k = 0; k < 32; k++) a += h1row[n][k] * W2s[k * 24 + f];
        }
        hs2out[(size_t)node * 32 + f] = (f < 24) ? f2bf(a * di) : (ushort_t)0;
    }
}

// gather layer 2 (rows padded to 32 bf16, packed uint2 loads, deep unroll) +
// fused finalize + node-MLP:  h2 = relu(dinv*(gather+self)+b2);
//   v = relu(h2@Wn1+bn1)@Wn2+bn2
__global__ __launch_bounds__(256) void gather2_kernel(
        const int* __restrict__ rowptr, const int* __restrict__ adj,
        const uint2* __restrict__ hs2q, const float* __restrict__ dinv,
        const float* __restrict__ b2,
        const float* __restrict__ Wn1, const float* __restrict__ bn1,
        const float* __restrict__ Wn2, const float* __restrict__ bn2,
        float* __restrict__ h2out, float* __restrict__ vout, int N) {
    __shared__ float Wn1s[24 * 16];
    __shared__ float b2s[32], bn1s[16], Wn2s[16];
    __shared__ float h2row[8][32];
    const int tid = threadIdx.x;
    for (int t = tid; t < 384; t += 256) Wn1s[t] = Wn1[t];
    if (tid < 32) b2s[tid] = (tid < 24) ? b2[tid] : 0.f;
    if (tid < 16) { bn1s[tid] = bn1[tid]; Wn2s[tid] = Wn2[tid]; }

    const int node = blockIdx.x * 8 + (tid >> 5);
    const int n = tid >> 5;
    const int l = tid & 31;
    const int f4 = l & 7;
    const int e4 = l >> 3;
    const bool valid = node < N;

    int beg = 0, cnt = 0;
    if (valid) { beg = rowptr[node]; cnt = rowptr[node + 1] - beg; }
    const int* ap = adj + beg;
    float a0 = 0.f, a1 = 0.f, a2 = 0.f, a3 = 0.f;
    int j = 0;
    for (; j + 16 <= cnt; j += 16) {
        int s0 = ap[j + e4];
        int s1 = ap[j + 4 + e4];
        int s2 = ap[j + 8 + e4];
        int s3 = ap[j + 12 + e4];
        uint2 v0 = hs2q[(size_t)s0 * 8 + f4];
        uint2 v1 = hs2q[(size_t)s1 * 8 + f4];
        uint2 v2 = hs2q[(size_t)s2 * 8 + f4];
        uint2 v3 = hs2q[(size_t)s3 * 8 + f4];
        a0 += lo16(v0.x); a1 += hi16(v0.x); a2 += lo16(v0.y); a3 += hi16(v0.y);
        a0 += lo16(v1.x); a1 += hi16(v1.x); a2 += lo16(v1.y); a3 += hi16(v1.y);
        a0 += lo16(v2.x); a1 += hi16(v2.x); a2 += lo16(v2.y); a3 += hi16(v2.y);
        a0 += lo16(v3.x); a1 += hi16(v3.x); a2 += lo16(v3.y); a3 += hi16(v3.y);
    }
    for (; j + 8 <= cnt; j += 8) {
        int s0 = ap[j + e4];
        int s1 = ap[j + 4 + e4];
        uint2 v0 = hs2q[(size_t)s0 * 8 + f4];
        uint2 v1 = hs2q[(size_t)s1 * 8 + f4];
        a0 += lo16(v0.x); a1 += hi16(v0.x); a2 += lo16(v0.y); a3 += hi16(v0.y);
        a0 += lo16(v1.x); a1 += hi16(v1.x); a2 += lo16(v1.y); a3 += hi16(v1.y);
    }
    for (; j + 4 <= cnt; j += 4) {
        int s0 = ap[j + e4];
        uint2 v0 = hs2q[(size_t)s0 * 8 + f4];
        a0 += lo16(v0.x); a1 += hi16(v0.x); a2 += lo16(v0.y); a3 += hi16(v0.y);
    }
    if (e4 < cnt - j) {
        int s0 = ap[j + e4];
        uint2 v0 = hs2q[(size_t)s0 * 8 + f4];
        a0 += lo16(v0.x); a1 += hi16(v0.x); a2 += lo16(v0.y); a3 += hi16(v0.y);
    }
    a0 += __shfl_xor(a0, 8);  a0 += __shfl_xor(a0, 16);
    a1 += __shfl_xor(a1, 8);  a1 += __shfl_xor(a1, 16);
    a2 += __shfl_xor(a2, 8);  a2 += __shfl_xor(a2, 16);
    a3 += __shfl_xor(a3, 8);  a3 += __shfl_xor(a3, 16);

    __syncthreads();   // weight/bias staging visibility

    if (valid) {
        float di = dinv[node];
        uint2 sv = hs2q[(size_t)node * 8 + f4];
        if (e4 == 0) {   // pad features (>=24): inputs all 0, b2s pad 0 -> h2 = 0
            h2row[n][4 * f4 + 0] = fmaxf(di * (a0 + lo16(sv.x)) + b2s[4 * f4 + 0], 0.f);
            h2row[n][4 * f4 + 1] = fmaxf(di * (a1 + hi16(sv.x)) + b2s[4 * f4 + 1], 0.f);
            h2row[n][4 * f4 + 2] = fmaxf(di * (a2 + lo16(sv.y)) + b2s[4 * f4 + 2], 0.f);
            h2row[n][4 * f4 + 3] = fmaxf(di * (a3 + hi16(sv.y)) + b2s[4 * f4 + 3], 0.f);
        }
    }
    // same-wave producer/consumer through LDS
    const int f = l;
    if (valid && f < 24) h2out[(size_t)node * 24 + f] = h2row[n][f];

    float val = 0.f;
    if (valid && f < 16) {
        float u = bn1s[f];
#pragma unroll
        for (int k = 0; k < 24; k++) u += h2row[n][k] * Wn1s[k * 16 + f];
        val = fmaxf(u, 0.f) * Wn2s[f];
    }
    val += __shfl_down(val, 8, 16);
    val += __shfl_down(val, 4, 16);
    val += __shfl_down(val, 2, 16);
    val += __shfl_down(val, 1, 16);
    if (valid && f == 0) vout[node] = val + bn2[0];
}

__device__ __forceinline__ int lower_bound_i(const int* __restrict__ a, int n, int key) {
    int lo = 0, hi = n;
    while (lo < hi) {
        int mid = (lo + hi) >> 1;
        if (a[mid] < key) lo = mid + 1; else hi = mid;
    }
    return lo;
}

// One block per graph (batch is sorted): segment softmax over nodes, mean pool,
// weighted pool, t-head, b-head pre-softmax. No global atomics.
__global__ __launch_bounds__(256) void graph_kernel(
        const float* __restrict__ v, const float* __restrict__ h2,
        const int* __restrict__ batch,
        const float* __restrict__ Wg, const float* __restrict__ bg,
        const float* __restrict__ Wt, const float* __restrict__ bt,
        const float* __restrict__ Wb1p, const float* __restrict__ bb1p,
        const float* __restrict__ Wb2p, const float* __restrict__ bb2p,
        float* __restrict__ out_t, float* __restrict__ out_n,
        float* __restrict__ bbpre, int N) {
    const int g = blockIdx.x;
    const int tid = threadIdx.x;
    const int lane = tid & 63;
    const int wid = tid >> 6;

    const int start = lower_bound_i(batch, N, g);
    const int end = lower_bound_i(batch, N, g + 1);

    __shared__ float sm[4];
    __shared__ float part[4][49];

    float m = -INFINITY;
    for (int idx = start + tid; idx < end; idx += 256) m = fmaxf(m, v[idx]);
#pragma unroll
    for (int off = 32; off > 0; off >>= 1) m = fmaxf(m, __shfl_down(m, off, 64));
    if (lane == 0) sm[wid] = m;
    __syncthreads();
    m = fmaxf(fmaxf(sm[0], sm[1]), fmaxf(sm[2], sm[3]));

    float s = 0.f;
    float hsum[24], wsum[24];
#pragma unroll
    for (int f = 0; f < 24; f++) { hsum[f] = 0.f; wsum[f] = 0.f; }
    for (int idx = start + tid; idx < end; idx += 256) {
        float e = __expf(v[idx] - m);
        s += e;
        const float4* hr = (const float4*)(h2 + (size_t)idx * 24);
#pragma unroll
        for (int q = 0; q < 6; q++) {
            float4 x4 = hr[q];
            hsum[4 * q] += x4.x;  wsum[4 * q] += e * x4.x;
            hsum[4 * q + 1] += x4.y; wsum[4 * q + 1] += e * x4.y;
            hsum[4 * q + 2] += x4.z; wsum[4 * q + 2] += e * x4.z;
            hsum[4 * q + 3] += x4.w; wsum[4 * q + 3] += e * x4.w;
        }
    }
#pragma unroll
    for (int off = 32; off > 0; off >>= 1) {
        s += __shfl_down(s, off, 64);
#pragma unroll
        for (int f = 0; f < 24; f++) {
            hsum[f] += __shfl_down(hsum[f], off, 64);
            wsum[f] += __shfl_down(wsum[f], off, 64);
        }
    }
    if (lane == 0) {
        part[wid][0] = s;
#pragma unroll
        for (int f = 0; f < 24; f++) { part[wid][1 + f] = hsum[f]; part[wid][25 + f] = wsum[f]; }
    }
    __syncthreads();
    const float stot = part[0][0] + part[1][0] + part[2][0] + part[3][0];
    const float invs = (stot > 0.f) ? 1.f / stot : 0.f;

    for (int idx = start + tid; idx < end; idx += 256)
        out_n[idx] = __expf(v[idx] - m) * invs;

    if (tid == 0) {
        float hsumT[24], wsumT[24];
#pragma unroll
        for (int f = 0; f < 24; f++) {
            hsumT[f] = part[0][1 + f] + part[1][1 + f] + part[2][1 + f] + part[3][1 + f];
            wsumT[f] = part[0][25 + f] + part[1][25 + f] + part[2][25 + f] + part[3][25 + f];
        }
        float cnt = (float)(end - start);
        float denom = fmaxf(cnt, 1.0f);

        float mean[24];
#pragma unroll
        for (int f = 0; f < 24; f++) mean[f] = hsumT[f] / denom;
        float gout[32];
        for (int o = 0; o < 32; o++) {
            float a = bg[o];
#pragma unroll
            for (int k = 0; k < 24; k++) a += mean[k] * Wg[k * 32 + o];
            gout[o] = a;
        }
        float t0 = bt[0], t1 = bt[1];
#pragma unroll
        for (int k = 0; k < 32; k++) { t0 += gout[k] * Wt[k * 2]; t1 += gout[k] * Wt[k * 2 + 1]; }
        float tm = fmaxf(t0, t1);
        float e0 = __expf(t0 - tm), e1 = __expf(t1 - tm);
        float ts = e0 + e1;
        out_t[g * 2 + 0] = e0 / ts;
        out_t[g * 2 + 1] = e1 / ts;

        float bf[24];
#pragma unroll
        for (int f = 0; f < 24; f++) bf[f] = wsumT[f] * invs;
        float u[16];
        for (int j = 0; j < 16; j++) {
            float a = bb1p[j];
#pragma unroll
            for (int k = 0; k < 24; k++) a += bf[k] * Wb1p[k * 16 + j];
            u[j] = fmaxf(a, 0.f);
        }
        for (int c = 0; c < 3; c++) {
            float a = bb2p[c];
#pragma unroll
            for (int j = 0; j < 16; j++) a += u[j] * Wb2p[j * 3 + c];
            bbpre[g * 3 + c] = a;
        }
    }
}

// column softmax over the 256 graphs (axis=0), 3 columns
__global__ __launch_bounds__(256) void bb_kernel(
        const float* __restrict__ bbpre, float* __restrict__ out_bb) {
    __shared__ float red[NG];
    int g = threadIdx.x;
#pragma unroll
    for (int c = 0; c < 3; c++) {
        float vv = bbpre[g * 3 + c];
        red[g] = vv;
        __syncthreads();
        for (int off = 128; off > 0; off >>= 1) {
            if (g < off) red[g] = fmaxf(red[g], red[g + off]);
            __syncthreads();
        }
        float m = red[0];
        __syncthreads();
        float e = __expf(vv - m);
        red[g] = e;
        __syncthreads();
        for (int off = 128; off > 0; off >>= 1) {
            if (g < off) red[g] += red[g + off];
            __syncthreads();
        }
        float ssum = red[0];
        __syncthreads();
        out_bb[g * 3 + c] = e / ssum;
    }
}

extern "C" void kernel_launch(void* const* d_in, const int* in_sizes, int n_in,
                              void* d_out, int out_size, void* d_ws, size_t ws_size,
                              hipStream_t stream) {
    const float* x   = (const float*)d_in[0];
    const int*   ei  = (const int*)d_in[1];    // [2,E] flat: row=ei[0..E), col=ei[E..2E)
    const int*   bat = (const int*)d_in[2];
    const float* W1  = (const float*)d_in[3];
    const float* b1  = (const float*)d_in[4];
    const float* W2  = (const float*)d_in[5];
    const float* b2  = (const float*)d_in[6];
    const float* Wg  = (const float*)d_in[7];
    const float* bg  = (const float*)d_in[8];
    const float* Wt  = (const float*)d_in[9];
    const float* bt  = (const float*)d_in[10];
    const float* Wn1 = (const float*)d_in[11];
    const float* bn1 = (const float*)d_in[12];
    const float* Wn2 = (const float*)d_in[13];
    const float* bn2 = (const float*)d_in[14];
    const float* Wb1 = (const float*)d_in[15];
    const float* bb1 = (const float*)d_in[16];
    const float* Wb2 = (const float*)d_in[17];
    const float* bb2 = (const float*)d_in[18];

    const int N = in_sizes[2];
    const int E = in_sizes[1] / 2;
    const int NB = (N + 511) >> 9;       // buckets of 512 nodes
    const int M = NB * NBLK;             // blockOff matrix size

    // workspace layout (4B units):
    // persistent: rowptr[N+1] | dinv[N] | adj[E] | bucketBase[NB+1]
    // transient (aliased union):
    //   build:   blockOff[M] | pairs[E]
    //   compute: bufA (hs1 bf16 16N -> h2 24N f32 + v N f32) | bufB[16N] (hs2 bf16 padded) | bbpre[768]
    auto rnd4 = [](size_t v) { return (v + 3) & ~(size_t)3; };
    size_t oRow = 0;
    size_t oDin = oRow + rnd4((size_t)N + 1);
    size_t oAdj = oDin + rnd4((size_t)N);
    size_t oBB  = oAdj + rnd4((size_t)E);
    size_t oT   = oBB + rnd4((size_t)NB + 1);
    size_t oPar = oT + rnd4((size_t)M);

    int*   wsi     = (int*)d_ws;
    float* wsf     = (float*)d_ws;
    int*   rowptr  = wsi + oRow;
    float* dinv    = wsf + oDin;
    int*   adj     = wsi + oAdj;
    int*   bbase   = wsi + oBB;
    int*   blkoff  = wsi + oT;
    int*   pairs   = wsi + oPar;
    float* bufA    = wsf + oT;                    // hs1 bf16 (16N units); later h2 (24N) + v (N)
    ushort_t* hs1b = (ushort_t*)bufA;
    float* bufB    = wsf + oT + (size_t)32 * N;   // hs2 bf16 padded (16N units)
    ushort_t* hs2b = (ushort_t*)bufB;
    float* bbpre   = wsf + oT + (size_t)48 * N;
    float* h2      = bufA;                        // hs1b dead once gather1 completes
    float* vbuf    = bufA + (size_t)24 * N;

    float* out_t  = (float*)d_out;          // [256,2]
    float* out_n  = out_t + 2 * NG;         // [N,1]
    float* out_bb = out_t + 2 * NG + N;     // [256,3]

    const int B = 256;

    // CSR build: bucketed counting sort; no global atomics, no memset
    hist_bucket_kernel<<<NBLK, B, 0, stream>>>(ei + E, blkoff, E, NB);
    offsets_kernel<<<1, 1024, 0, stream>>>(blkoff, bbase, NB);
    scatter_pairs_kernel<<<NBLK, B, 0, stream>>>(ei, blkoff, pairs, E, NB);
    csr_bucket_kernel<<<NB, B, 0, stream>>>(pairs, bbase, rowptr, adj, dinv, N, E);

    // GCN + heads (bf16 staging rows, packed uint2 gathers, fp32 accumulation)
    hs1_kernel<<<(N * 32 + B - 1) / B, B, 0, stream>>>(x, W1, dinv, hs1b, N);
    gather1_kernel<<<(N + 7) / 8, B, 0, stream>>>(rowptr, adj, (const uint2*)hs1b,
                                                  dinv, b1, W2, hs2b, N);
    gather2_kernel<<<(N + 7) / 8, B, 0, stream>>>(rowptr, adj, (const uint2*)hs2b,
                                                  dinv, b2, Wn1, bn1, Wn2, bn2, h2, vbuf, N);
    graph_kernel<<<NG, B, 0, stream>>>(vbuf, h2, bat, Wg, bg, Wt, bt,
                                       Wb1, bb1, Wb2, bb2, out_t, out_n, bbpre, N);
    bb_kernel<<<1, B, 0, stream>>>(bbpre, out_bb);
}

// Round 8
// 372.523 us; speedup vs baseline: 1.0226x; 1.0226x over previous
//
#include <hip/hip_runtime.h>
#include <math.h>

#define NG 256     // NUM_GRAPHS
#define NBLK 256   // blocks in histogram / pair-scatter passes
// bucket = target >> 8 (256 nodes/bucket, NB<=512); src packs in 17 bits (N <= 131072)

// fp8-e4m3 staging scales (powers of 2: exactly invertible)
#define S1F 16.0f
#define IS1F 0.0625f
#define S2F 64.0f
#define IS2F 0.015625f

typedef __attribute__((ext_vector_type(2))) float f32x2;

__device__ __forceinline__ unsigned enc4(float f0, float f1, float f2, float f3) {
    int r = __builtin_amdgcn_cvt_pk_fp8_f32(f0, f1, 0, false);
    r = __builtin_amdgcn_cvt_pk_fp8_f32(f2, f3, r, true);
    return (unsigned)r;
}
__device__ __forceinline__ void acc8(uint2 v, float (&a)[8]) {
    f32x2 p0 = __builtin_amdgcn_cvt_pk_f32_fp8((int)v.x, false);
    f32x2 p1 = __builtin_amdgcn_cvt_pk_f32_fp8((int)v.x, true);
    f32x2 p2 = __builtin_amdgcn_cvt_pk_f32_fp8((int)v.y, false);
    f32x2 p3 = __builtin_amdgcn_cvt_pk_f32_fp8((int)v.y, true);
    a[0] += p0[0]; a[1] += p0[1]; a[2] += p1[0]; a[3] += p1[1];
    a[4] += p2[0]; a[5] += p2[1]; a[6] += p3[0]; a[7] += p3[1];
}

// ---------------------------------------------------------------------------
// K1: per-block histogram of edge targets into NB buckets (LDS atomics only)
__global__ __launch_bounds__(256) void hist_bucket_kernel(
        const int* __restrict__ col, int* __restrict__ blockOff, int E, int NB) {
    __shared__ int h[512];
    h[threadIdx.x] = 0; h[threadIdx.x + 256] = 0;
    __syncthreads();
    const int chunk = (E + NBLK - 1) / NBLK;
    const int beg = blockIdx.x * chunk;
    const int end = min(beg + chunk, E);
    for (int e = beg + threadIdx.x; e < end; e += 256)
        atomicAdd(&h[col[e] >> 8], 1);
    __syncthreads();
    for (int t = threadIdx.x; t < NB; t += 256)
        blockOff[t * NBLK + blockIdx.x] = h[t];
}

// K2 (one block, 1024 thr): raw counts -> absolute scatter offsets (NB <= 512)
__global__ __launch_bounds__(1024) void offsets_kernel(
        int* __restrict__ blockOff, int* __restrict__ bucketBase, int NB) {
    __shared__ int bsum[512];
    __shared__ int bbase[512];
    const int t = threadIdx.x;
    const int w = t >> 6, ln = t & 63;
    if (t < 512) bsum[t] = 0;
    __syncthreads();
    for (int b = w; b < NB; b += 16) {           // per-bucket scan of 256 counts
        int idx = b * NBLK + ln * 4;
        int c0 = blockOff[idx + 0], c1 = blockOff[idx + 1];
        int c2 = blockOff[idx + 2], c3 = blockOff[idx + 3];
        int s = c0 + c1 + c2 + c3;
        int inc = s;
#pragma unroll
        for (int d = 1; d < 64; d <<= 1) {
            int u = __shfl_up(inc, d, 64);
            if (ln >= d) inc += u;
        }
        int ex = inc - s;
        blockOff[idx + 0] = ex;
        blockOff[idx + 1] = ex + c0;
        blockOff[idx + 2] = ex + c0 + c1;
        blockOff[idx + 3] = ex + c0 + c1 + c2;
        if (ln == 63) bsum[b] = inc;
    }
    __syncthreads();
    if (w == 0) {                                // scan 512 bucket totals, 8/lane
        int i0 = 8 * ln;
        int vv[8]; int s = 0;
#pragma unroll
        for (int k = 0; k < 8; k++) { vv[k] = bsum[i0 + k]; s += vv[k]; }
        int inc = s;
#pragma unroll
        for (int d = 1; d < 64; d <<= 1) {
            int u = __shfl_up(inc, d, 64);
            if (ln >= d) inc += u;
        }
        int ex = inc - s;
#pragma unroll
        for (int k = 0; k < 8; k++) { bbase[i0 + k] = ex; ex += vv[k]; }
        int tot = __shfl(inc, 63, 64);
        if (ln == 0) bucketBase[NB] = tot;
    }
    __syncthreads();
    for (int b = w; b < NB; b += 16) {           // add bucket bases
        int base = bbase[b];
        int idx = b * NBLK + ln * 4;
        blockOff[idx + 0] += base;
        blockOff[idx + 1] += base;
        blockOff[idx + 2] += base;
        blockOff[idx + 3] += base;
        if (ln == 0) bucketBase[b] = base;
    }
}

// K3: scatter packed (local_tgt<<17 | src) pairs, grouped by bucket (LDS cursors)
__global__ __launch_bounds__(256) void scatter_pairs_kernel(
        const int* __restrict__ ei, const int* __restrict__ blockOff,
        int* __restrict__ pairs, int E, int NB) {
    __shared__ int cur[512];
    for (int t = threadIdx.x; t < NB; t += 256)
        cur[t] = blockOff[t * NBLK + blockIdx.x];
    __syncthreads();
    const int chunk = (E + NBLK - 1) / NBLK;
    const int beg = blockIdx.x * chunk;
    const int end = min(beg + chunk, E);
    for (int e = beg + threadIdx.x; e < end; e += 256) {
        int src = ei[e];
        int tgt = ei[E + e];
        int pos = atomicAdd(&cur[tgt >> 8], 1);
        pairs[pos] = (int)(((unsigned)(tgt & 255) << 17) | (unsigned)src);
    }
}

// K4: one block per bucket (256 nodes): LDS hist + scan -> rowptr, dinv, adj
__global__ __launch_bounds__(256) void csr_bucket_kernel(
        const int* __restrict__ pairs, const int* __restrict__ bucketBase,
        int* __restrict__ rowptr, int* __restrict__ adj,
        float* __restrict__ dinv, int N, int E) {
    __shared__ int h[256];
    __shared__ int sc[256];
    __shared__ int cur[256];
    const int b = blockIdx.x, t = threadIdx.x;
    const int base = bucketBase[b];
    const int end = bucketBase[b + 1];
    h[t] = 0;
    __syncthreads();
    for (int i = base + t; i < end; i += 256)
        atomicAdd(&h[(unsigned)pairs[i] >> 17], 1);
    __syncthreads();
    const int v = h[t];
    sc[t] = v;
    __syncthreads();
    for (int o = 1; o < 256; o <<= 1) {
        int u = (t >= o) ? sc[t - o] : 0;
        __syncthreads();
        sc[t] += u;
        __syncthreads();
    }
    const int ex = sc[t] - v;
    const int node = (b << 8) + t;
    if (node < N) {
        rowptr[node] = base + ex;
        dinv[node] = rsqrtf((float)v + 1.0f);
    }
    cur[t] = base + ex;
    __syncthreads();
    for (int i = base + t; i < end; i += 256) {
        unsigned p = (unsigned)pairs[i];
        int pos = atomicAdd(&cur[p >> 17], 1);
        adj[pos] = (int)(p & 0x1FFFFu);
    }
    if (b == 0 && t == 0) rowptr[N] = E;
}

// ---------------------------------------------------------------------------
// hs1[i][f] = fp8( (x[i]@W1)[f] * dinv[i] * S1 )   (32 feats -> 32 B rows)
__global__ __launch_bounds__(256) void hs1_kernel(
        const float* __restrict__ x, const float* __restrict__ W,
        const float* __restrict__ dinv, unsigned* __restrict__ hs, int N) {
    __shared__ float Ws[32 * 32];
    __shared__ float tmp[8][32];
    for (int t = threadIdx.x; t < 1024; t += blockDim.x) Ws[t] = W[t];
    __syncthreads();
    const int tid = threadIdx.x;
    const int node = blockIdx.x * 8 + (tid >> 5);
    const int n = tid >> 5, f = tid & 31;
    if (node < N) {
        const float* xr = x + (size_t)node * 32;
        float acc = 0.f;
#pragma unroll
        for (int k = 0; k < 32; k++) acc += xr[k] * Ws[k * 32 + f];
        tmp[n][f] = acc * dinv[node] * S1F;
        if (f < 8)   // same-wave producer/consumer
            hs[(size_t)node * 8 + f] = enc4(tmp[n][4 * f], tmp[n][4 * f + 1],
                                            tmp[n][4 * f + 2], tmp[n][4 * f + 3]);
    }
}

// gather layer 1 (fp8 rows, 32 B: 4 lanes/row, 8 edge slots, 16 edges/iter)
//   h1 = relu(dinv*(gather+self)/S1 + b1)   (LDS only, fp32)
//   hs2[i] = fp8( dinv*(h1@W2) * S2 )       (24 feats, padded to 32 B)
__global__ __launch_bounds__(256) void gather1_kernel(
        const int* __restrict__ rowptr, const int* __restrict__ adj,
        const uint2* __restrict__ hs1q, const float* __restrict__ dinv,
        const float* __restrict__ b1, const float* __restrict__ W2,
        unsigned* __restrict__ hs2out, int N) {
    __shared__ float W2s[32 * 24];
    __shared__ float b1s[32];
    __shared__ float h1row[8][32];
    __shared__ float hs2t[8][32];
    const int tid = threadIdx.x;
    for (int t = tid; t < 768; t += 256) W2s[t] = W2[t];
    if (tid < 32) b1s[tid] = b1[tid];

    const int node = blockIdx.x * 8 + (tid >> 5);
    const int n = tid >> 5;
    const int l = tid & 31;
    const int f8 = l & 3;        // feature octet: features 8*f8 .. 8*f8+7
    const int e8 = l >> 2;       // edge slot 0..7
    const bool valid = node < N;

    int beg = 0, cnt = 0;
    if (valid) { beg = rowptr[node]; cnt = rowptr[node + 1] - beg; }
    const int* ap = adj + beg;
    float a[8] = {0.f, 0.f, 0.f, 0.f, 0.f, 0.f, 0.f, 0.f};
    int j = 0;
    for (; j + 16 <= cnt; j += 16) {            // 16 edges/iter, 2 loads in flight
        int s0 = ap[j + e8];
        int s1 = ap[j + 8 + e8];
        uint2 v0 = hs1q[(size_t)s0 * 4 + f8];
        uint2 v1 = hs1q[(size_t)s1 * 4 + f8];
        acc8(v0, a); acc8(v1, a);
    }
    for (; j + 8 <= cnt; j += 8) {
        int s0 = ap[j + e8];
        acc8(hs1q[(size_t)s0 * 4 + f8], a);
    }
    if (e8 < cnt - j) {                          // tail 0..7 edges
        int s0 = ap[j + e8];
        acc8(hs1q[(size_t)s0 * 4 + f8], a);
    }
#pragma unroll
    for (int k = 0; k < 8; k++) {                // fold 8 edge slots (lane bits 2,3,4)
        a[k] += __shfl_xor(a[k], 4);
        a[k] += __shfl_xor(a[k], 8);
        a[k] += __shfl_xor(a[k], 16);
    }

    __syncthreads();   // weight/bias staging visibility (all threads reach here)

    float di = 0.f;
    if (valid) {
        di = dinv[node];
        if (e8 == 0) {                           // lanes l<4 finalize 8 feats each
            float sv[8] = {0.f, 0.f, 0.f, 0.f, 0.f, 0.f, 0.f, 0.f};
            acc8(hs1q[(size_t)node * 4 + f8], sv);   // self-loop term
            const float c = di * IS1F;
#pragma unroll
            for (int k = 0; k < 8; k++)
                h1row[n][8 * f8 + k] = fmaxf(c * (a[k] + sv[k]) + b1s[8 * f8 + k], 0.f);
        }
    }
    // same-wave producer/consumer through LDS: no barrier needed
    if (valid) {
        float aa = 0.f;
        if (l < 24) {
#pragma unroll
            for (int k = 0; k < 32; k++) aa += h1row[n][k] * W2s[k * 24 + l];
        }
        hs2t[n][l] = (l < 24) ? aa * di * S2F : 0.f;
        if (l < 8)
            hs2out[(size_t)node * 8 + l] = enc4(hs2t[n][4 * l], hs2t[n][4 * l + 1],
                                                hs2t[n][4 * l + 2], hs2t[n][4 * l + 3]);
    }
}

// gather layer 2 (fp8 rows, 32 B) + fused finalize + node-MLP:
//   h2 = relu(dinv*(gather+self)/S2 + b2);  v = relu(h2@Wn1+bn1)@Wn2+bn2
__global__ __launch_bounds__(256) void gather2_kernel(
        const int* __restrict__ rowptr, const int* __restrict__ adj,
        const uint2* __restrict__ hs2q, const float* __restrict__ dinv,
        const float* __restrict__ b2,
        const float* __restrict__ Wn1, const float* __restrict__ bn1,
        const float* __restrict__ Wn2, const float* __restrict__ bn2,
        float* __restrict__ h2out, float* __restrict__ vout, int N) {
    __shared__ float Wn1s[24 * 16];
    __shared__ float b2s[32], bn1s[16], Wn2s[16];
    __shared__ float h2row[8][32];
    const int tid = threadIdx.x;
    for (int t = tid; t < 384; t += 256) Wn1s[t] = Wn1[t];
    if (tid < 32) b2s[tid] = (tid < 24) ? b2[tid] : 0.f;
    if (tid < 16) { bn1s[tid] = bn1[tid]; Wn2s[tid] = Wn2[tid]; }

    const int node = blockIdx.x * 8 + (tid >> 5);
    const int n = tid >> 5;
    const int l = tid & 31;
    const int f8 = l & 3;
    const int e8 = l >> 2;
    const bool valid = node < N;

    int beg = 0, cnt = 0;
    if (valid) { beg = rowptr[node]; cnt = rowptr[node + 1] - beg; }
    const int* ap = adj + beg;
    float a[8] = {0.f, 0.f, 0.f, 0.f, 0.f, 0.f, 0.f, 0.f};
    int j = 0;
    for (; j + 16 <= cnt; j += 16) {
        int s0 = ap[j + e8];
        int s1 = ap[j + 8 + e8];
        uint2 v0 = hs2q[(size_t)s0 * 4 + f8];
        uint2 v1 = hs2q[(size_t)s1 * 4 + f8];
        acc8(v0, a); acc8(v1, a);
    }
    for (; j + 8 <= cnt; j += 8) {
        int s0 = ap[j + e8];
        acc8(hs2q[(size_t)s0 * 4 + f8], a);
    }
    if (e8 < cnt - j) {
        int s0 = ap[j + e8];
        acc8(hs2q[(size_t)s0 * 4 + f8], a);
    }
#pragma unroll
    for (int k = 0; k < 8; k++) {
        a[k] += __shfl_xor(a[k], 4);
        a[k] += __shfl_xor(a[k], 8);
        a[k] += __shfl_xor(a[k], 16);
    }

    __syncthreads();   // weight/bias staging visibility

    if (valid && e8 == 0) {
        float di = dinv[node];
        float sv[8] = {0.f, 0.f, 0.f, 0.f, 0.f, 0.f, 0.f, 0.f};
        acc8(hs2q[(size_t)node * 4 + f8], sv);
        const float c = di * IS2F;
#pragma unroll
        for (int k = 0; k < 8; k++)   // pad feats (>=24): staged 0, b2s 0 -> h2 0
            h2row[n][8 * f8 + k] = fmaxf(c * (a[k] + sv[k]) + b2s[8 * f8 + k], 0.f);
    }
    // same-wave producer/consumer through LDS
    if (valid && l < 24) h2out[(size_t)node * 24 + l] = h2row[n][l];

    float val = 0.f;
    if (valid && l < 16) {
        float u = bn1s[l];
#pragma unroll
        for (int k = 0; k < 24; k++) u += h2row[n][k] * Wn1s[k * 16 + l];
        val = fmaxf(u, 0.f) * Wn2s[l];
    }
    val += __shfl_down(val, 8, 16);
    val += __shfl_down(val, 4, 16);
    val += __shfl_down(val, 2, 16);
    val += __shfl_down(val, 1, 16);
    if (valid && l == 0) vout[node] = val + bn2[0];
}

__device__ __forceinline__ int lower_bound_i(const int* __restrict__ a, int n, int key) {
    int lo = 0, hi = n;
    while (lo < hi) {
        int mid = (lo + hi) >> 1;
        if (a[mid] < key) lo = mid + 1; else hi = mid;
    }
    return lo;
}

// One block per graph (batch is sorted): segment softmax over nodes, mean pool,
// weighted pool, t-head, b-head pre-softmax. No global atomics.
__global__ __launch_bounds__(256) void graph_kernel(
        const float* __restrict__ v, const float* __restrict__ h2,
        const int* __restrict__ batch,
        const float* __restrict__ Wg, const float* __restrict__ bg,
        const float* __restrict__ Wt, const float* __restrict__ bt,
        const float* __restrict__ Wb1p, const float* __restrict__ bb1p,
        const float* __restrict__ Wb2p, const float* __restrict__ bb2p,
        float* __restrict__ out_t, float* __restrict__ out_n,
        float* __restrict__ bbpre, int N) {
    const int g = blockIdx.x;
    const int tid = threadIdx.x;
    const int lane = tid & 63;
    const int wid = tid >> 6;

    const int start = lower_bound_i(batch, N, g);
    const int end = lower_bound_i(batch, N, g + 1);

    __shared__ float sm[4];
    __shared__ float part[4][49];

    float m = -INFINITY;
    for (int idx = start + tid; idx < end; idx += 256) m = fmaxf(m, v[idx]);
#pragma unroll
    for (int off = 32; off > 0; off >>= 1) m = fmaxf(m, __shfl_down(m, off, 64));
    if (lane == 0) sm[wid] = m;
    __syncthreads();
    m = fmaxf(fmaxf(sm[0], sm[1]), fmaxf(sm[2], sm[3]));

    float s = 0.f;
    float hsum[24], wsum[24];
#pragma unroll
    for (int f = 0; f < 24; f++) { hsum[f] = 0.f; wsum[f] = 0.f; }
    for (int idx = start + tid; idx < end; idx += 256) {
        float e = __expf(v[idx] - m);
        s += e;
        const float4* hr = (const float4*)(h2 + (size_t)idx * 24);
#pragma unroll
        for (int q = 0; q < 6; q++) {
            float4 x4 = hr[q];
            hsum[4 * q] += x4.x;  wsum[4 * q] += e * x4.x;
            hsum[4 * q + 1] += x4.y; wsum[4 * q + 1] += e * x4.y;
            hsum[4 * q + 2] += x4.z; wsum[4 * q + 2] += e * x4.z;
            hsum[4 * q + 3] += x4.w; wsum[4 * q + 3] += e * x4.w;
        }
    }
#pragma unroll
    for (int off = 32; off > 0; off >>= 1) {
        s += __shfl_down(s, off, 64);
#pragma unroll
        for (int f = 0; f < 24; f++) {
            hsum[f] += __shfl_down(hsum[f], off, 64);
            wsum[f] += __shfl_down(wsum[f], off, 64);
        }
    }
    if (lane == 0) {
        part[wid][0] = s;
#pragma unroll
        for (int f = 0; f < 24; f++) { part[wid][1 + f] = hsum[f]; part[wid][25 + f] = wsum[f]; }
    }
    __syncthreads();
    const float stot = part[0][0] + part[1][0] + part[2][0] + part[3][0];
    const float invs = (stot > 0.f) ? 1.f / stot : 0.f;

    for (int idx = start + tid; idx < end; idx += 256)
        out_n[idx] = __expf(v[idx] - m) * invs;

    if (tid == 0) {
        float hsumT[24], wsumT[24];
#pragma unroll
        for (int f = 0; f < 24; f++) {
            hsumT[f] = part[0][1 + f] + part[1][1 + f] + part[2][1 + f] + part[3][1 + f];
            wsumT[f] = part[0][25 + f] + part[1][25 + f] + part[2][25 + f] + part[3][25 + f];
        }
        float cnt = (float)(end - start);
        float denom = fmaxf(cnt, 1.0f);

        float mean[24];
#pragma unroll
        for (int f = 0; f < 24; f++) mean[f] = hsumT[f] / denom;
        float gout[32];
        for (int o = 0; o < 32; o++) {
            float a = bg[o];
#pragma unroll
            for (int k = 0; k < 24; k++) a += mean[k] * Wg[k * 32 + o];
            gout[o] = a;
        }
        float t0 = bt[0], t1 = bt[1];
#pragma unroll
        for (int k = 0; k < 32; k++) { t0 += gout[k] * Wt[k * 2]; t1 += gout[k] * Wt[k * 2 + 1]; }
        float tm = fmaxf(t0, t1);
        float e0 = __expf(t0 - tm), e1 = __expf(t1 - tm);
        float ts = e0 + e1;
        out_t[g * 2 + 0] = e0 / ts;
        out_t[g * 2 + 1] = e1 / ts;

        float bf[24];
#pragma unroll
        for (int f = 0; f < 24; f++) bf[f] = wsumT[f] * invs;
        float u[16];
        for (int j = 0; j < 16; j++) {
            float a = bb1p[j];
#pragma unroll
            for (int k = 0; k < 24; k++) a += bf[k] * Wb1p[k * 16 + j];
            u[j] = fmaxf(a, 0.f);
        }
        for (int c = 0; c < 3; c++) {
            float a = bb2p[c];
#pragma unroll
            for (int j = 0; j < 16; j++) a += u[j] * Wb2p[j * 3 + c];
            bbpre[g * 3 + c] = a;
        }
    }
}

// column softmax over the 256 graphs (axis=0), 3 columns
__global__ __launch_bounds__(256) void bb_kernel(
        const float* __restrict__ bbpre, float* __restrict__ out_bb) {
    __shared__ float red[NG];
    int g = threadIdx.x;
#pragma unroll
    for (int c = 0; c < 3; c++) {
        float vv = bbpre[g * 3 + c];
        red[g] = vv;
        __syncthreads();
        for (int off = 128; off > 0; off >>= 1) {
            if (g < off) red[g] = fmaxf(red[g], red[g + off]);
            __syncthreads();
        }
        float m = red[0];
        __syncthreads();
        float e = __expf(vv - m);
        red[g] = e;
        __syncthreads();
        for (int off = 128; off > 0; off >>= 1) {
            if (g < off) red[g] += red[g + off];
            __syncthreads();
        }
        float ssum = red[0];
        __syncthreads();
        out_bb[g * 3 + c] = e / ssum;
    }
}

extern "C" void kernel_launch(void* const* d_in, const int* in_sizes, int n_in,
                              void* d_out, int out_size, void* d_ws, size_t ws_size,
                              hipStream_t stream) {
    const float* x   = (const float*)d_in[0];
    const int*   ei  = (const int*)d_in[1];    // [2,E] flat: row=ei[0..E), col=ei[E..2E)
    const int*   bat = (const int*)d_in[2];
    const float* W1  = (const float*)d_in[3];
    const float* b1  = (const float*)d_in[4];
    const float* W2  = (const float*)d_in[5];
    const float* b2  = (const float*)d_in[6];
    const float* Wg  = (const float*)d_in[7];
    const float* bg  = (const float*)d_in[8];
    const float* Wt  = (const float*)d_in[9];
    const float* bt  = (const float*)d_in[10];
    const float* Wn1 = (const float*)d_in[11];
    const float* bn1 = (const float*)d_in[12];
    const float* Wn2 = (const float*)d_in[13];
    const float* bn2 = (const float*)d_in[14];
    const float* Wb1 = (const float*)d_in[15];
    const float* bb1 = (const float*)d_in[16];
    const float* Wb2 = (const float*)d_in[17];
    const float* bb2 = (const float*)d_in[18];

    const int N = in_sizes[2];
    const int E = in_sizes[1] / 2;
    const int NB = (N + 255) >> 8;       // buckets of 256 nodes
    const int M = NB * NBLK;             // blockOff matrix size

    // workspace layout (4B units):
    // persistent: rowptr[N+1] | dinv[N] | adj[E] | bucketBase[NB+1]
    // transient (aliased union):
    //   build:   blockOff[M] | pairs[E]
    //   compute: hs1 fp8 (2N) -> h2 f32 (24N) + v (N) ; hs2 fp8 at +26N (2N) ; bbpre at +28N
    auto rnd4 = [](size_t v) { return (v + 3) & ~(size_t)3; };
    size_t oRow = 0;
    size_t oDin = oRow + rnd4((size_t)N + 1);
    size_t oAdj = oDin + rnd4((size_t)N);
    size_t oBB  = oAdj + rnd4((size_t)E);
    size_t oT   = oBB + rnd4((size_t)NB + 1);
    size_t oPar = oT + rnd4((size_t)M);

    int*   wsi     = (int*)d_ws;
    float* wsf     = (float*)d_ws;
    int*   rowptr  = wsi + oRow;
    float* dinv    = wsf + oDin;
    int*   adj     = wsi + oAdj;
    int*   bbase   = wsi + oBB;
    int*   blkoff  = wsi + oT;
    int*   pairs   = wsi + oPar;
    unsigned* hs1b = (unsigned*)(wsf + oT);                  // 2N units (8B-aligned: oT mult of 4)
    float* h2      = wsf + oT;                               // reuses hs1b after gather1
    float* vbuf    = wsf + oT + (size_t)24 * N;
    unsigned* hs2b = (unsigned*)(wsf + oT + (size_t)26 * N); // 2N units
    float* bbpre   = wsf + oT + (size_t)28 * N;

    float* out_t  = (float*)d_out;          // [256,2]
    float* out_n  = out_t + 2 * NG;         // [N,1]
    float* out_bb = out_t + 2 * NG + N;     // [256,3]

    const int B = 256;

    // CSR build: bucketed counting sort; no global atomics, no memset
    hist_bucket_kernel<<<NBLK, B, 0, stream>>>(ei + E, blkoff, E, NB);
    offsets_kernel<<<1, 1024, 0, stream>>>(blkoff, bbase, NB);
    scatter_pairs_kernel<<<NBLK, B, 0, stream>>>(ei, blkoff, pairs, E, NB);
    csr_bucket_kernel<<<NB, B, 0, stream>>>(pairs, bbase, rowptr, adj, dinv, N, E);

    // GCN + heads (fp8 staging rows, fp32 accumulation)
    hs1_kernel<<<(N + 7) / 8, B, 0, stream>>>(x, W1, dinv, hs1b, N);
    gather1_kernel<<<(N + 7) / 8, B, 0, stream>>>(rowptr, adj, (const uint2*)hs1b,
                                                  dinv, b1, W2, hs2b, N);
    gather2_kernel<<<(N + 7) / 8, B, 0, stream>>>(rowptr, adj, (const uint2*)hs2b,
                                                  dinv, b2, Wn1, bn1, Wn2, bn2, h2, vbuf, N);
    graph_kernel<<<NG, B, 0, stream>>>(vbuf, h2, bat, Wg, bg, Wt, bt,
                                       Wb1, bb1, Wb2, bb2, out_t, out_n, bbpre, N);
    bb_kernel<<<1, B, 0, stream>>>(bbpre, out_bb);
}

// Round 9
// 334.822 us; speedup vs baseline: 1.1378x; 1.1126x over previous
//
#include <hip/hip_runtime.h>
#include <math.h>

#define NG 256     // NUM_GRAPHS
#define NBLK 256   // blocks in histogram / pair-scatter passes
// bucket = target >> 8 (256 nodes/bucket, NB<=512); src packs in 17 bits (N <= 131072)

// fp8-e4m3 staging scales (powers of 2: exactly invertible)
#define S1F 16.0f
#define IS1F 0.0625f
#define S2F 64.0f
#define IS2F 0.015625f

typedef __attribute__((ext_vector_type(2))) float f32x2;

__device__ __forceinline__ unsigned enc4(float f0, float f1, float f2, float f3) {
    int r = __builtin_amdgcn_cvt_pk_fp8_f32(f0, f1, 0, false);
    r = __builtin_amdgcn_cvt_pk_fp8_f32(f2, f3, r, true);
    return (unsigned)r;
}
__device__ __forceinline__ void acc8(uint2 v, float (&a)[8]) {
    f32x2 p0 = __builtin_amdgcn_cvt_pk_f32_fp8((int)v.x, false);
    f32x2 p1 = __builtin_amdgcn_cvt_pk_f32_fp8((int)v.x, true);
    f32x2 p2 = __builtin_amdgcn_cvt_pk_f32_fp8((int)v.y, false);
    f32x2 p3 = __builtin_amdgcn_cvt_pk_f32_fp8((int)v.y, true);
    a[0] += p0[0]; a[1] += p0[1]; a[2] += p1[0]; a[3] += p1[1];
    a[4] += p2[0]; a[5] += p2[1]; a[6] += p3[0]; a[7] += p3[1];
}

// ---------------------------------------------------------------------------
// K1: per-block histogram of edge targets into NB buckets (LDS atomics), then
// reserve this block's range in each bucket via one global atomic per bucket.
__global__ __launch_bounds__(256) void hist_bucket_kernel(
        const int* __restrict__ col, int* __restrict__ blockOff,
        int* __restrict__ bucketTot, int E, int NB) {
    __shared__ int h[512];
    h[threadIdx.x] = 0; h[threadIdx.x + 256] = 0;
    __syncthreads();
    const int chunk = (E + NBLK - 1) / NBLK;
    const int beg = blockIdx.x * chunk;
    const int end = min(beg + chunk, E);
    for (int e = beg + threadIdx.x; e < end; e += 256)
        atomicAdd(&h[col[e] >> 8], 1);
    __syncthreads();
    for (int t = threadIdx.x; t < NB; t += 256) {
        int off = atomicAdd(&bucketTot[t], h[t]);   // reserve range (order arbitrary)
        blockOff[t * NBLK + blockIdx.x] = off;
    }
}

// K2: tiny exclusive scan over bucketTot[NB] -> bucketBase[NB+1]  (NB <= 512)
__global__ __launch_bounds__(512) void tiny_scan_kernel(
        const int* __restrict__ bucketTot, int* __restrict__ bucketBase, int NB) {
    __shared__ int part[512];
    const int t = threadIdx.x;
    int v = (t < NB) ? bucketTot[t] : 0;
    part[t] = v;
    __syncthreads();
    for (int o = 1; o < 512; o <<= 1) {
        int u = (t >= o) ? part[t - o] : 0;
        __syncthreads();
        part[t] += u;
        __syncthreads();
    }
    if (t < NB) bucketBase[t] = part[t] - v;   // exclusive
    if (t == NB) bucketBase[NB] = part[NB - 1];
    if (t == 511 && NB == 512) bucketBase[NB] = part[511];
}

// K3: scatter packed (local_tgt<<17 | src) pairs, grouped by bucket (LDS cursors)
__global__ __launch_bounds__(256) void scatter_pairs_kernel(
        const int* __restrict__ ei, const int* __restrict__ blockOff,
        const int* __restrict__ bucketBase, int* __restrict__ pairs, int E, int NB) {
    __shared__ int cur[512];
    for (int t = threadIdx.x; t < NB; t += 256)
        cur[t] = bucketBase[t] + blockOff[t * NBLK + blockIdx.x];
    __syncthreads();
    const int chunk = (E + NBLK - 1) / NBLK;
    const int beg = blockIdx.x * chunk;
    const int end = min(beg + chunk, E);
    for (int e = beg + threadIdx.x; e < end; e += 256) {
        int src = ei[e];
        int tgt = ei[E + e];
        int pos = atomicAdd(&cur[tgt >> 8], 1);
        pairs[pos] = (int)(((unsigned)(tgt & 255) << 17) | (unsigned)src);
    }
}

// K4: one block per bucket (256 nodes): LDS hist + scan -> rowptr, dinv, adj
__global__ __launch_bounds__(256) void csr_bucket_kernel(
        const int* __restrict__ pairs, const int* __restrict__ bucketBase,
        int* __restrict__ rowptr, int* __restrict__ adj,
        float* __restrict__ dinv, int N, int E) {
    __shared__ int h[256];
    __shared__ int sc[256];
    __shared__ int cur[256];
    const int b = blockIdx.x, t = threadIdx.x;
    const int base = bucketBase[b];
    const int end = bucketBase[b + 1];
    h[t] = 0;
    __syncthreads();
    for (int i = base + t; i < end; i += 256)
        atomicAdd(&h[(unsigned)pairs[i] >> 17], 1);
    __syncthreads();
    const int v = h[t];
    sc[t] = v;
    __syncthreads();
    for (int o = 1; o < 256; o <<= 1) {
        int u = (t >= o) ? sc[t - o] : 0;
        __syncthreads();
        sc[t] += u;
        __syncthreads();
    }
    const int ex = sc[t] - v;
    const int node = (b << 8) + t;
    if (node < N) {
        rowptr[node] = base + ex;
        dinv[node] = rsqrtf((float)v + 1.0f);
    }
    cur[t] = base + ex;
    __syncthreads();
    for (int i = base + t; i < end; i += 256) {
        unsigned p = (unsigned)pairs[i];
        int pos = atomicAdd(&cur[p >> 17], 1);
        adj[pos] = (int)(p & 0x1FFFFu);
    }
    if (b == 0 && t == 0) rowptr[N] = E;
}

// ---------------------------------------------------------------------------
// hs1[i][f] = fp8( (x[i]@W1)[f] * dinv[i] * S1 )   (32 feats -> 32 B rows)
__global__ __launch_bounds__(256) void hs1_kernel(
        const float* __restrict__ x, const float* __restrict__ W,
        const float* __restrict__ dinv, unsigned* __restrict__ hs, int N) {
    __shared__ float Ws[32 * 32];
    __shared__ float tmp[8][32];
    for (int t = threadIdx.x; t < 1024; t += blockDim.x) Ws[t] = W[t];
    __syncthreads();
    const int tid = threadIdx.x;
    const int node = blockIdx.x * 8 + (tid >> 5);
    const int n = tid >> 5, f = tid & 31;
    if (node < N) {
        const float* xr = x + (size_t)node * 32;
        float acc = 0.f;
#pragma unroll
        for (int k = 0; k < 32; k++) acc += xr[k] * Ws[k * 32 + f];
        tmp[n][f] = acc * dinv[node] * S1F;
        if (f < 8)   // same-wave producer/consumer
            hs[(size_t)node * 8 + f] = enc4(tmp[n][4 * f], tmp[n][4 * f + 1],
                                            tmp[n][4 * f + 2], tmp[n][4 * f + 3]);
    }
}

// gather layer 1 (fp8 rows, 32 B: 4 lanes/row, 8 edge slots, 16 edges/iter)
//   h1 = relu(dinv*(gather+self)/S1 + b1)   (LDS only, fp32)
//   hs2[i] = fp8( dinv*(h1@W2) * S2 )       (24 feats, padded to 32 B)
__global__ __launch_bounds__(256) void gather1_kernel(
        const int* __restrict__ rowptr, const int* __restrict__ adj,
        const uint2* __restrict__ hs1q, const float* __restrict__ dinv,
        const float* __restrict__ b1, const float* __restrict__ W2,
        unsigned* __restrict__ hs2out, int N) {
    __shared__ float W2s[32 * 24];
    __shared__ float b1s[32];
    __shared__ float h1row[8][32];
    __shared__ float hs2t[8][32];
    const int tid = threadIdx.x;
    for (int t = tid; t < 768; t += 256) W2s[t] = W2[t];
    if (tid < 32) b1s[tid] = b1[tid];

    const int node = blockIdx.x * 8 + (tid >> 5);
    const int n = tid >> 5;
    const int l = tid & 31;
    const int f8 = l & 3;        // feature octet: features 8*f8 .. 8*f8+7
    const int e8 = l >> 2;       // edge slot 0..7
    const bool valid = node < N;

    int beg = 0, cnt = 0;
    if (valid) { beg = rowptr[node]; cnt = rowptr[node + 1] - beg; }
    const int* ap = adj + beg;
    float a[8] = {0.f, 0.f, 0.f, 0.f, 0.f, 0.f, 0.f, 0.f};
    int j = 0;
    for (; j + 16 <= cnt; j += 16) {            // 16 edges/iter, 2 loads in flight
        int s0 = ap[j + e8];
        int s1 = ap[j + 8 + e8];
        uint2 v0 = hs1q[(size_t)s0 * 4 + f8];
        uint2 v1 = hs1q[(size_t)s1 * 4 + f8];
        acc8(v0, a); acc8(v1, a);
    }
    for (; j + 8 <= cnt; j += 8) {
        int s0 = ap[j + e8];
        acc8(hs1q[(size_t)s0 * 4 + f8], a);
    }
    if (e8 < cnt - j) {                          // tail 0..7 edges
        int s0 = ap[j + e8];
        acc8(hs1q[(size_t)s0 * 4 + f8], a);
    }
#pragma unroll
    for (int k = 0; k < 8; k++) {                // fold 8 edge slots (lane bits 2,3,4)
        a[k] += __shfl_xor(a[k], 4);
        a[k] += __shfl_xor(a[k], 8);
        a[k] += __shfl_xor(a[k], 16);
    }

    __syncthreads();   // weight/bias staging visibility (all threads reach here)

    float di = 0.f;
    if (valid) {
        di = dinv[node];
        if (e8 == 0) {                           // lanes l<4 finalize 8 feats each
            float sv[8] = {0.f, 0.f, 0.f, 0.f, 0.f, 0.f, 0.f, 0.f};
            acc8(hs1q[(size_t)node * 4 + f8], sv);   // self-loop term
            const float c = di * IS1F;
#pragma unroll
            for (int k = 0; k < 8; k++)
                h1row[n][8 * f8 + k] = fmaxf(c * (a[k] + sv[k]) + b1s[8 * f8 + k], 0.f);
        }
    }
    // same-wave producer/consumer through LDS: no barrier needed
    if (valid) {
        float aa = 0.f;
        if (l < 24) {
#pragma unroll
            for (int k = 0; k < 32; k++) aa += h1row[n][k] * W2s[k * 24 + l];
        }
        hs2t[n][l] = (l < 24) ? aa * di * S2F : 0.f;
        if (l < 8)
            hs2out[(size_t)node * 8 + l] = enc4(hs2t[n][4 * l], hs2t[n][4 * l + 1],
                                                hs2t[n][4 * l + 2], hs2t[n][4 * l + 3]);
    }
}

// gather layer 2 (fp8 rows, 32 B) + fused finalize + node-MLP:
//   h2 = relu(dinv*(gather+self)/S2 + b2);  v = relu(h2@Wn1+bn1)@Wn2+bn2
__global__ __launch_bounds__(256) void gather2_kernel(
        const int* __restrict__ rowptr, const int* __restrict__ adj,
        const uint2* __restrict__ hs2q, const float* __restrict__ dinv,
        const float* __restrict__ b2,
        const float* __restrict__ Wn1, const float* __restrict__ bn1,
        const float* __restrict__ Wn2, const float* __restrict__ bn2,
        float* __restrict__ h2out, float* __restrict__ vout, int N) {
    __shared__ float Wn1s[24 * 16];
    __shared__ float b2s[32], bn1s[16], Wn2s[16];
    __shared__ float h2row[8][32];
    const int tid = threadIdx.x;
    for (int t = tid; t < 384; t += 256) Wn1s[t] = Wn1[t];
    if (tid < 32) b2s[tid] = (tid < 24) ? b2[tid] : 0.f;
    if (tid < 16) { bn1s[tid] = bn1[tid]; Wn2s[tid] = Wn2[tid]; }

    const int node = blockIdx.x * 8 + (tid >> 5);
    const int n = tid >> 5;
    const int l = tid & 31;
    const int f8 = l & 3;
    const int e8 = l >> 2;
    const bool valid = node < N;

    int beg = 0, cnt = 0;
    if (valid) { beg = rowptr[node]; cnt = rowptr[node + 1] - beg; }
    const int* ap = adj + beg;
    float a[8] = {0.f, 0.f, 0.f, 0.f, 0.f, 0.f, 0.f, 0.f};
    int j = 0;
    for (; j + 16 <= cnt; j += 16) {
        int s0 = ap[j + e8];
        int s1 = ap[j + 8 + e8];
        uint2 v0 = hs2q[(size_t)s0 * 4 + f8];
        uint2 v1 = hs2q[(size_t)s1 * 4 + f8];
        acc8(v0, a); acc8(v1, a);
    }
    for (; j + 8 <= cnt; j += 8) {
        int s0 = ap[j + e8];
        acc8(hs2q[(size_t)s0 * 4 + f8], a);
    }
    if (e8 < cnt - j) {
        int s0 = ap[j + e8];
        acc8(hs2q[(size_t)s0 * 4 + f8], a);
    }
#pragma unroll
    for (int k = 0; k < 8; k++) {
        a[k] += __shfl_xor(a[k], 4);
        a[k] += __shfl_xor(a[k], 8);
        a[k] += __shfl_xor(a[k], 16);
    }

    __syncthreads();   // weight/bias staging visibility

    if (valid && e8 == 0) {
        float di = dinv[node];
        float sv[8] = {0.f, 0.f, 0.f, 0.f, 0.f, 0.f, 0.f, 0.f};
        acc8(hs2q[(size_t)node * 4 + f8], sv);
        const float c = di * IS2F;
#pragma unroll
        for (int k = 0; k < 8; k++)   // pad feats (>=24): staged 0, b2s 0 -> h2 0
            h2row[n][8 * f8 + k] = fmaxf(c * (a[k] + sv[k]) + b2s[8 * f8 + k], 0.f);
    }
    // same-wave producer/consumer through LDS
    if (valid && l < 24) h2out[(size_t)node * 24 + l] = h2row[n][l];

    float val = 0.f;
    if (valid && l < 16) {
        float u = bn1s[l];
#pragma unroll
        for (int k = 0; k < 24; k++) u += h2row[n][k] * Wn1s[k * 16 + l];
        val = fmaxf(u, 0.f) * Wn2s[l];
    }
    val += __shfl_down(val, 8, 16);
    val += __shfl_down(val, 4, 16);
    val += __shfl_down(val, 2, 16);
    val += __shfl_down(val, 1, 16);
    if (valid && l == 0) vout[node] = val + bn2[0];
}

__device__ __forceinline__ int lower_bound_i(const int* __restrict__ a, int n, int key) {
    int lo = 0, hi = n;
    while (lo < hi) {
        int mid = (lo + hi) >> 1;
        if (a[mid] < key) lo = mid + 1; else hi = mid;
    }
    return lo;
}

// One block per graph (batch is sorted): segment softmax over nodes, mean pool,
// weighted pool, t-head, b-head pre-softmax. No global atomics.
__global__ __launch_bounds__(256) void graph_kernel(
        const float* __restrict__ v, const float* __restrict__ h2,
        const int* __restrict__ batch,
        const float* __restrict__ Wg, const float* __restrict__ bg,
        const float* __restrict__ Wt, const float* __restrict__ bt,
        const float* __restrict__ Wb1p, const float* __restrict__ bb1p,
        const float* __restrict__ Wb2p, const float* __restrict__ bb2p,
        float* __restrict__ out_t, float* __restrict__ out_n,
        float* __restrict__ bbpre, int N) {
    const int g = blockIdx.x;
    const int tid = threadIdx.x;
    const int lane = tid & 63;
    const int wid = tid >> 6;

    const int start = lower_bound_i(batch, N, g);
    const int end = lower_bound_i(batch, N, g + 1);

    __shared__ float sm[4];
    __shared__ float part[4][49];

    float m = -INFINITY;
    for (int idx = start + tid; idx < end; idx += 256) m = fmaxf(m, v[idx]);
#pragma unroll
    for (int off = 32; off > 0; off >>= 1) m = fmaxf(m, __shfl_down(m, off, 64));
    if (lane == 0) sm[wid] = m;
    __syncthreads();
    m = fmaxf(fmaxf(sm[0], sm[1]), fmaxf(sm[2], sm[3]));

    float s = 0.f;
    float hsum[24], wsum[24];
#pragma unroll
    for (int f = 0; f < 24; f++) { hsum[f] = 0.f; wsum[f] = 0.f; }
    for (int idx = start + tid; idx < end; idx += 256) {
        float e = __expf(v[idx] - m);
        s += e;
        const float4* hr = (const float4*)(h2 + (size_t)idx * 24);
#pragma unroll
        for (int q = 0; q < 6; q++) {
            float4 x4 = hr[q];
            hsum[4 * q] += x4.x;  wsum[4 * q] += e * x4.x;
            hsum[4 * q + 1] += x4.y; wsum[4 * q + 1] += e * x4.y;
            hsum[4 * q + 2] += x4.z; wsum[4 * q + 2] += e * x4.z;
            hsum[4 * q + 3] += x4.w; wsum[4 * q + 3] += e * x4.w;
        }
    }
#pragma unroll
    for (int off = 32; off > 0; off >>= 1) {
        s += __shfl_down(s, off, 64);
#pragma unroll
        for (int f = 0; f < 24; f++) {
            hsum[f] += __shfl_down(hsum[f], off, 64);
            wsum[f] += __shfl_down(wsum[f], off, 64);
        }
    }
    if (lane == 0) {
        part[wid][0] = s;
#pragma unroll
        for (int f = 0; f < 24; f++) { part[wid][1 + f] = hsum[f]; part[wid][25 + f] = wsum[f]; }
    }
    __syncthreads();
    const float stot = part[0][0] + part[1][0] + part[2][0] + part[3][0];
    const float invs = (stot > 0.f) ? 1.f / stot : 0.f;

    for (int idx = start + tid; idx < end; idx += 256)
        out_n[idx] = __expf(v[idx] - m) * invs;

    if (tid == 0) {
        float hsumT[24], wsumT[24];
#pragma unroll
        for (int f = 0; f < 24; f++) {
            hsumT[f] = part[0][1 + f] + part[1][1 + f] + part[2][1 + f] + part[3][1 + f];
            wsumT[f] = part[0][25 + f] + part[1][25 + f] + part[2][25 + f] + part[3][25 + f];
        }
        float cnt = (float)(end - start);
        float denom = fmaxf(cnt, 1.0f);

        float mean[24];
#pragma unroll
        for (int f = 0; f < 24; f++) mean[f] = hsumT[f] / denom;
        float gout[32];
        for (int o = 0; o < 32; o++) {
            float a = bg[o];
#pragma unroll
            for (int k = 0; k < 24; k++) a += mean[k] * Wg[k * 32 + o];
            gout[o] = a;
        }
        float t0 = bt[0], t1 = bt[1];
#pragma unroll
        for (int k = 0; k < 32; k++) { t0 += gout[k] * Wt[k * 2]; t1 += gout[k] * Wt[k * 2 + 1]; }
        float tm = fmaxf(t0, t1);
        float e0 = __expf(t0 - tm), e1 = __expf(t1 - tm);
        float ts = e0 + e1;
        out_t[g * 2 + 0] = e0 / ts;
        out_t[g * 2 + 1] = e1 / ts;

        float bf[24];
#pragma unroll
        for (int f = 0; f < 24; f++) bf[f] = wsumT[f] * invs;
        float u[16];
        for (int j = 0; j < 16; j++) {
            float a = bb1p[j];
#pragma unroll
            for (int k = 0; k < 24; k++) a += bf[k] * Wb1p[k * 16 + j];
            u[j] = fmaxf(a, 0.f);
        }
        for (int c = 0; c < 3; c++) {
            float a = bb2p[c];
#pragma unroll
            for (int j = 0; j < 16; j++) a += u[j] * Wb2p[j * 3 + c];
            bbpre[g * 3 + c] = a;
        }
    }
}

// column softmax over the 256 graphs (axis=0), 3 columns
__global__ __launch_bounds__(256) void bb_kernel(
        const float* __restrict__ bbpre, float* __restrict__ out_bb) {
    __shared__ float red[NG];
    int g = threadIdx.x;
#pragma unroll
    for (int c = 0; c < 3; c++) {
        float vv = bbpre[g * 3 + c];
        red[g] = vv;
        __syncthreads();
        for (int off = 128; off > 0; off >>= 1) {
            if (g < off) red[g] = fmaxf(red[g], red[g + off]);
            __syncthreads();
        }
        float m = red[0];
        __syncthreads();
        float e = __expf(vv - m);
        red[g] = e;
        __syncthreads();
        for (int off = 128; off > 0; off >>= 1) {
            if (g < off) red[g] += red[g + off];
            __syncthreads();
        }
        float ssum = red[0];
        __syncthreads();
        out_bb[g * 3 + c] = e / ssum;
    }
}

extern "C" void kernel_launch(void* const* d_in, const int* in_sizes, int n_in,
                              void* d_out, int out_size, void* d_ws, size_t ws_size,
                              hipStream_t stream) {
    const float* x   = (const float*)d_in[0];
    const int*   ei  = (const int*)d_in[1];    // [2,E] flat: row=ei[0..E), col=ei[E..2E)
    const int*   bat = (const int*)d_in[2];
    const float* W1  = (const float*)d_in[3];
    const float* b1  = (const float*)d_in[4];
    const float* W2  = (const float*)d_in[5];
    const float* b2  = (const float*)d_in[6];
    const float* Wg  = (const float*)d_in[7];
    const float* bg  = (const float*)d_in[8];
    const float* Wt  = (const float*)d_in[9];
    const float* bt  = (const float*)d_in[10];
    const float* Wn1 = (const float*)d_in[11];
    const float* bn1 = (const float*)d_in[12];
    const float* Wn2 = (const float*)d_in[13];
    const float* bn2 = (const float*)d_in[14];
    const float* Wb1 = (const float*)d_in[15];
    const float* bb1 = (const float*)d_in[16];
    const float* Wb2 = (const float*)d_in[17];
    const float* bb2 = (const float*)d_in[18];

    const int N = in_sizes[2];
    const int E = in_sizes[1] / 2;
    const int NB = (N + 255) >> 8;       // buckets of 256 nodes
    const int M = NB * NBLK;             // blockOff matrix size

    // workspace layout (4B units):
    // persistent: rowptr[N+1] | dinv[N] | adj[E] | bucketBase[NB+1] | bucketTot[NB]
    // transient (aliased union):
    //   build:   blockOff[M] | pairs[E]
    //   compute: hs1 fp8 (2N) -> h2 f32 (24N) + v (N) ; hs2 fp8 at +26N (2N) ; bbpre at +28N
    auto rnd4 = [](size_t v) { return (v + 3) & ~(size_t)3; };
    size_t oRow = 0;
    size_t oDin = oRow + rnd4((size_t)N + 1);
    size_t oAdj = oDin + rnd4((size_t)N);
    size_t oBB  = oAdj + rnd4((size_t)E);
    size_t oTot = oBB + rnd4((size_t)NB + 1);
    size_t oT   = oTot + rnd4((size_t)NB);
    size_t oPar = oT + rnd4((size_t)M);

    int*   wsi     = (int*)d_ws;
    float* wsf     = (float*)d_ws;
    int*   rowptr  = wsi + oRow;
    float* dinv    = wsf + oDin;
    int*   adj     = wsi + oAdj;
    int*   bbase   = wsi + oBB;
    int*   btot    = wsi + oTot;
    int*   blkoff  = wsi + oT;
    int*   pairs   = wsi + oPar;
    unsigned* hs1b = (unsigned*)(wsf + oT);                  // 2N units (8B-aligned: oT mult of 4)
    float* h2      = wsf + oT;                               // reuses hs1b region after gather1
    float* vbuf    = wsf + oT + (size_t)24 * N;
    unsigned* hs2b = (unsigned*)(wsf + oT + (size_t)26 * N); // 2N units
    float* bbpre   = wsf + oT + (size_t)28 * N;

    float* out_t  = (float*)d_out;          // [256,2]
    float* out_n  = out_t + 2 * NG;         // [N,1]
    float* out_bb = out_t + 2 * NG + N;     // [256,3]

    const int B = 256;

    // CSR build: bucketed counting sort; only the tiny NB-sized scan is serial
    hipMemsetAsync(btot, 0, (size_t)NB * sizeof(int), stream);
    hist_bucket_kernel<<<NBLK, B, 0, stream>>>(ei + E, blkoff, btot, E, NB);
    tiny_scan_kernel<<<1, 512, 0, stream>>>(btot, bbase, NB);
    scatter_pairs_kernel<<<NBLK, B, 0, stream>>>(ei, blkoff, bbase, pairs, E, NB);
    csr_bucket_kernel<<<NB, B, 0, stream>>>(pairs, bbase, rowptr, adj, dinv, N, E);

    // GCN + heads (fp8 staging rows, fp32 accumulation)
    hs1_kernel<<<(N + 7) / 8, B, 0, stream>>>(x, W1, dinv, hs1b, N);
    gather1_kernel<<<(N + 7) / 8, B, 0, stream>>>(rowptr, adj, (const uint2*)hs1b,
                                                  dinv, b1, W2, hs2b, N);
    gather2_kernel<<<(N + 7) / 8, B, 0, stream>>>(rowptr, adj, (const uint2*)hs2b,
                                                  dinv, b2, Wn1, bn1, Wn2, bn2, h2, vbuf, N);
    graph_kernel<<<NG, B, 0, stream>>>(vbuf, h2, bat, Wg, bg, Wt, bt,
                                       Wb1, bb1, Wb2, bb2, out_t, out_n, bbpre, N);
    bb_kernel<<<1, B, 0, stream>>>(bbpre, out_bb);
}